// Round 14
// baseline (675.083 us; speedup 1.0000x reference)
//
#include <hip/hip_runtime.h>

#define LPTS 4096
#define NTOKS 512
#define TILE 32
#define CAP (LPTS + TILE)      // coord arrays sized CAP: compacted + pad tile
#define GRID_B 2208            // fused blocks (grid-stride over tiles)
#define PREP_BLKS 32
#define MAGIC 0x5EED1234u

#define LOG2E   1.44269504f
#define EPS_S   (1e-6f * LOG2E)
#define CLAMP_S (25.f * LOG2E)
#define CUT15_S (15.f * LOG2E)
#define CUT30_S (30.f * LOG2E)
#define PAD_BIG 1e15f

// ws layout:
//   wsi[5]         Lv (plain store by prep block 31; atomic-loaded by consumers)
//   wsi[16..48)    per-prep-block MAGIC tokens (idempotent readiness barrier)
//   ws[64..64+160) prep partials: [block b][k] k=0..3 mse_d, k=4 mask count
//   OFF_GT:   float4 cgt4[CAP] (gt xyz scaled by log2e, meta=tok|isna<<16)
//   OFF_PX/PY/PZ: float4 per-point pred coords scaled by log2e (lanes d=0..3)
//   OFF_PART: float partials[GRID_B][5]
#define OFF_GT 1024
#define OFF_PX (OFF_GT + CAP * 16)
#define OFF_PY (OFF_PX + CAP * 16)
#define OFF_PZ (OFF_PY + CAP * 16)
#define OFF_PART (OFF_PZ + CAP * 16)

static __device__ __forceinline__ float nan0(float x) {
  if (!(x == x)) return 0.f;
  return fminf(fmaxf(x, -3.402823466e38f), 3.402823466e38f);
}

// sum of 4 sigmoids = N(e)/D(e), e = exp(delta) = 2^(delta_scaled)
static __device__ __forceinline__ float sterm(float dx, float dy, float dz, float tmp) {
  float d2 = fmaf(dx, dx, fmaf(dy, dy, dz * dz));
  float pd = __builtin_amdgcn_sqrtf(d2);
  float delta = fminf(fabsf(pd + tmp), CLAMP_S);   // scaled domain
  float e = __builtin_amdgcn_exp2f(delta);         // = exp(delta_unscaled)
  float e2 = e * e;
  float e3 = e2 * e;
  float e4 = e2 * e2;
  float Nn = fmaf(0.0366994762f, e3, fmaf(0.7506558488f, e2, fmaf(3.3841830690f, e, 4.f)));
  float Dd = fmaf(0.00055308437f, e4,
             fmaf(0.0366994762f, e3, fmaf(0.3753279244f, e2, fmaf(1.1280610231f, e, 1.f))));
  return Nn * __builtin_amdgcn_rcpf(Dd);           // pad rows/cols: Dd=inf -> s=0 (finite)
}

// ---- Kernel 1: fused prep (blocks 0..31, token-released) + pair tiles ----
__global__ __launch_bounds__(128) void fused_kernel(
    const float* __restrict__ XL, const float* __restrict__ Xgt,
    const void* __restrict__ crd, const void* __restrict__ dna,
    const void* __restrict__ rna, const void* __restrict__ lig,
    const void* __restrict__ tok, float* __restrict__ ws) {
  int b = blockIdx.x, t = threadIdx.x;
  int* wsi = (int*)ws;
  __shared__ float4 sg[TILE], sx[TILE], sy[TILE], sz[TILE];
  __shared__ float bred[2][5];
  __shared__ int sflags[5];
  __shared__ int sw[2], wcnt2[2];
  __shared__ int sready;
  int lane = t & 63, wid = t >> 6;

  if (b < PREP_BLKS) {
    // ================= prep phase (1 point per thread) =================
    int l = b * 128 + t;
    const int* toki = (const int*)tok;
    const int* crdi = (const int*)crd;
    const unsigned char* crdB = (const unsigned char*)crd;
    if (t < 5) sflags[t] = 0;
    __syncthreads();
    {
      int f0 = 0;
      for (int i = t; i < LPTS / 2; i += 128) f0 |= (toki[2 * i + 1] != 0);
      if (f0) atomicOr(&sflags[0], 1);
      int f1 = 0;
      for (int i = t; i < LPTS / 4; i += 128) f1 |= ((unsigned)crdi[i] > 1u);
      if (f1) atomicOr(&sflags[1], 1);
      // t in [0,128) == NTOKS/4 words exactly
      if ((unsigned)((const int*)dna)[t] > 1u) atomicOr(&sflags[2], 1);
      if ((unsigned)((const int*)rna)[t] > 1u) atomicOr(&sflags[3], 1);
      if ((unsigned)((const int*)lig)[t] > 1u) atomicOr(&sflags[4], 1);
    }
    __syncthreads();
    bool tok64 = sflags[0] == 0;
    bool crdb = sflags[1] != 0, dnab = sflags[2] != 0,
         rnab = sflags[3] != 0, ligb = sflags[4] != 0;
    // deterministic prefix over [0, b*128)
    int pre = 0;
    for (int i = t; i < b * 128; i += 128)
      pre += crdb ? (crdB[i] != 0) : (crdi[i] != 0);
    // own point
    int tk = tok64 ? toki[2 * l] : toki[l];
    int tki = min(max(tk, 0), NTOKS - 1);
    int m  = crdb ? (crdB[l] != 0) : (crdi[l] != 0);
    int dn = (dnab ? (int)((const unsigned char*)dna)[tki] : ((const int*)dna)[tki]) != 0;
    int rn = (rnab ? (int)((const unsigned char*)rna)[tki] : ((const int*)rna)[tki]) != 0;
    int lg = (ligb ? (int)((const unsigned char*)lig)[tki] : ((const int*)lig)[tki]) != 0;
    float w = (1.f + 5.f * dn + 5.f * rn + 10.f * lg) * (float)m;
    float gx = nan0(Xgt[3 * l + 0]);
    float gy = nan0(Xgt[3 * l + 1]);
    float gz = nan0(Xgt[3 * l + 2]);
    int meta = (tk & 0xFFFF) | ((dn | rn) << 16);
    float xs[4], ys[4], zs[4], v[5];
#pragma unroll
    for (int d = 0; d < 4; ++d) {
      xs[d] = XL[(d * LPTS + l) * 3 + 0];
      ys[d] = XL[(d * LPTS + l) * 3 + 1];
      zs[d] = XL[(d * LPTS + l) * 3 + 2];
      float dx = xs[d] - gx, dy = ys[d] - gy, dz = zs[d] - gz;
      v[d] = w * (dx * dx + dy * dy + dz * dz);   // MSE unscaled
    }
    v[4] = (float)m;
    // block scan (2 waves)
    unsigned long long bal = __ballot(m != 0);
    int p = pre;
#pragma unroll
    for (int off = 32; off; off >>= 1) p += __shfl_down(p, off, 64);
    if (lane == 0) { sw[wid] = p; wcnt2[wid] = __popcll(bal); }
    __syncthreads();
    int block_base = sw[0] + sw[1];
    int wbase = block_base + (wid ? wcnt2[0] : 0);
    int pos = wbase + __popcll(bal & ((1ull << lane) - 1ull));
    float4* cgt4 = (float4*)((char*)ws + OFF_GT);
    float4* cpx  = (float4*)((char*)ws + OFF_PX);
    float4* cpy  = (float4*)((char*)ws + OFF_PY);
    float4* cpz  = (float4*)((char*)ws + OFF_PZ);
    if (m) {
      cgt4[pos] = make_float4(gx * LOG2E, gy * LOG2E, gz * LOG2E, __int_as_float(meta));
      cpx[pos] = make_float4(xs[0] * LOG2E, xs[1] * LOG2E, xs[2] * LOG2E, xs[3] * LOG2E);
      cpy[pos] = make_float4(ys[0] * LOG2E, ys[1] * LOG2E, ys[2] * LOG2E, ys[3] * LOG2E);
      cpz[pos] = make_float4(zs[0] * LOG2E, zs[1] * LOG2E, zs[2] * LOG2E, zs[3] * LOG2E);
    }
    if (b == PREP_BLKS - 1) {
      int Lv = block_base + wcnt2[0] + wcnt2[1];
      if (t == 0) wsi[5] = Lv;
      if (t < TILE) {   // pad: huge gt -> pm=0; zero pred; sentinel meta
        cgt4[Lv + t] = make_float4(PAD_BIG, PAD_BIG, PAD_BIG, __int_as_float(0x7FFFFFFF));
        float4 z = make_float4(0.f, 0.f, 0.f, 0.f);
        cpx[Lv + t] = z; cpy[Lv + t] = z; cpz[Lv + t] = z;
      }
    }
    // MSE partials
#pragma unroll
    for (int k = 0; k < 5; ++k) {
      float x = v[k];
#pragma unroll
      for (int off = 32; off; off >>= 1) x += __shfl_down(x, off, 64);
      v[k] = x;
    }
    if (lane == 0)
      for (int k = 0; k < 5; ++k) bred[wid][k] = v[k];
    __syncthreads();
    if (t == 0)
      for (int k = 0; k < 5; ++k) ws[64 + b * 5 + k] = bred[0][k] + bred[1][k];
    // release: every wave drains its stores, then one token store
    asm volatile("s_waitcnt vmcnt(0)" ::: "memory");
    __syncthreads();
    if (t == 0)
      __hip_atomic_store((unsigned*)&wsi[16 + b], MAGIC, __ATOMIC_RELEASE,
                         __HIP_MEMORY_SCOPE_AGENT);
  }

  // ============ idempotent token barrier (free when tokens valid) ============
  if (t == 0) sready = 0;
  __syncthreads();
  for (;;) {
    int ok = 1;
    if (t < PREP_BLKS)
      ok = (__hip_atomic_load((const unsigned*)&wsi[16 + t], __ATOMIC_ACQUIRE,
                              __HIP_MEMORY_SCOPE_AGENT) == MAGIC);
    unsigned long long bal = __ballot(ok != 0);   // wave 0 holds all 32 checks
    if (t == 0) sready = (bal == ~0ull);
    __syncthreads();
    if (sready) break;
    __builtin_amdgcn_s_sleep(8);
    __syncthreads();
  }

  // ================= pair phase (R7 body) =================
  const int Lv = __hip_atomic_load(&wsi[5], __ATOMIC_RELAXED, __HIP_MEMORY_SCOPE_AGENT);
  const int NT = (Lv + TILE - 1) >> 5;
  const int NA = NT * (NT + 1) / 2;
  const float4* cgt4 = (const float4*)((const char*)ws + OFF_GT);
  const float4* cpx  = (const float4*)((const char*)ws + OFF_PX);
  const float4* cpy  = (const float4*)((const char*)ws + OFF_PY);
  const float4* cpz  = (const float4*)((const char*)ws + OFF_PZ);
  int r = t & 31, g = t >> 5;      // g in 0..3, 8 cols each
  float a0 = 0.f, a1 = 0.f, a2 = 0.f, a3 = 0.f, a4 = 0.f;
  for (int e = blockIdx.x; e < NA; e += GRID_B) {
    int tj = (int)((__builtin_amdgcn_sqrtf(8.f * (float)e + 1.f) - 1.f) * 0.5f);
    while ((tj + 1) * (tj + 2) / 2 <= e) ++tj;
    while (tj * (tj + 1) / 2 > e) --tj;
    int ti = e - tj * (tj + 1) / 2;
    int i0 = ti * TILE, j0 = tj * TILE;
    __syncthreads();
    if (t < 32) sg[t] = cgt4[j0 + t];
    else if (t < 64) sx[t - 32] = cpx[j0 + t - 32];
    else if (t < 96) sy[t - 64] = cpy[j0 + t - 64];
    else sz[t - 96] = cpz[j0 + t - 96];
    __syncthreads();
    int i = i0 + r;
    float4 rg = cgt4[i], rx = cpx[i], ry = cpy[i], rz = cpz[i];
    int rmeta = __float_as_int(rg.w);
    float cutoff = (rmeta & 0x10000) ? CUT30_S : CUT15_S;
    bool diag = (ti == tj);
#pragma unroll
    for (int k = 0; k < 8; ++k) {
      int jj = g * 8 + k;
      float4 cg = sg[jj];
      float dgx = rg.x - cg.x, dgy = rg.y - cg.y, dgz = rg.z - cg.z;
      float gd = __builtin_amdgcn_sqrtf(fmaf(dgx, dgx, fmaf(dgy, dgy, dgz * dgz)));
      bool pm = (gd > 0.f) & (gd < cutoff) & (rmeta != __float_as_int(cg.w));
      if (diag) pm = pm & (jj > r);
      float pmf = pm ? 1.f : 0.f;
      float tmp = EPS_S - gd;
      float4 cx = sx[jj], cy = sy[jj], cz = sz[jj];
      float s0 = sterm(rx.x - cx.x, ry.x - cy.x, rz.x - cz.x, tmp);
      float s1 = sterm(rx.y - cx.y, ry.y - cy.y, rz.y - cz.y, tmp);
      float s2 = sterm(rx.z - cx.z, ry.z - cy.z, rz.z - cz.z, tmp);
      float s3 = sterm(rx.w - cx.w, ry.w - cy.w, rz.w - cz.w, tmp);
      a0 = fmaf(s0, pmf, a0);
      a1 = fmaf(s1, pmf, a1);
      a2 = fmaf(s2, pmf, a2);
      a3 = fmaf(s3, pmf, a3);
      a4 += pmf;
    }
  }
  // block reduce (2 waves) -> one plain store (kernel boundary = release)
  float v[5] = {a0, a1, a2, a3, a4};
#pragma unroll
  for (int k = 0; k < 5; ++k) {
    float x = v[k];
#pragma unroll
    for (int off = 32; off; off >>= 1) x += __shfl_down(x, off, 64);
    v[k] = x;
  }
  __syncthreads();
  if (lane == 0)
    for (int k = 0; k < 5; ++k) bred[wid][k] = v[k];
  __syncthreads();
  if (t == 0) {
    float* part = (float*)((char*)ws + OFF_PART);
#pragma unroll
    for (int k = 0; k < 5; ++k)
      part[blockIdx.x * 5 + k] = bred[0][k] + bred[1][k];
  }
}

// ---------------- Kernel 2: final reduce + scalar assembly ----------------
__global__ __launch_bounds__(1024) void final_kernel(
    const float* __restrict__ ws, const float* __restrict__ t_in,
    float* __restrict__ out) {
  int t = threadIdx.x;
  const float* part = (const float*)((const char*)ws + OFF_PART);
  float u[5] = {0.f, 0.f, 0.f, 0.f, 0.f};
  for (int i = t; i < GRID_B; i += 1024) {
#pragma unroll
    for (int k = 0; k < 5; ++k) u[k] += part[i * 5 + k];
  }
#pragma unroll
  for (int k = 0; k < 5; ++k) {
    float x = u[k];
#pragma unroll
    for (int off = 32; off; off >>= 1) x += __shfl_down(x, off, 64);
    u[k] = x;
  }
  __shared__ float bred[16][5];
  int wid = t >> 6, lane = t & 63;
  if (lane == 0)
    for (int k = 0; k < 5; ++k) bred[wid][k] = u[k];
  __syncthreads();
  if (t == 0) {
    float ssum[5];
#pragma unroll
    for (int k = 0; k < 5; ++k) {
      float x = 0.f;
      for (int q = 0; q < 16; ++q) x += bred[q][k];
      ssum[k] = x;
    }
    float mse[4] = {0.f, 0.f, 0.f, 0.f};
    float mask_sum = 0.f;
    for (int b = 0; b < PREP_BLKS; ++b) {
#pragma unroll
      for (int d = 0; d < 4; ++d) mse[d] += ws[64 + b * 5 + d];
      mask_sum += ws[64 + b * 5 + 4];
    }
    float pm_sum = ssum[4];
    float tot = 0.f;
#pragma unroll
    for (int d = 0; d < 4; ++d) {
      float lmse = (mse[d] * (1.f / 3.f)) / (mask_sum + 1e-4f);
      float td = t_in[d];
      float lam = (td * td + 256.f) / (256.f * td * td);
      float ldiff = fminf(lam * lmse, 2.f);
      float lddt = 0.25f * ssum[d] / (pm_sum + 1e-6f);
      tot += 0.25f * (ldiff + (1.f - lddt));
    }
    out[0] = 4.f * tot;
  }
}

extern "C" void kernel_launch(void* const* d_in, const int* in_sizes, int n_in,
                              void* d_out, int out_size, void* d_ws, size_t ws_size,
                              hipStream_t stream) {
  (void)in_sizes; (void)n_in; (void)out_size; (void)ws_size;
  const float* XL  = (const float*)d_in[0];
  const float* Xgt = (const float*)d_in[1];
  float* ws = (float*)d_ws;
  float* out = (float*)d_out;
  fused_kernel<<<GRID_B, 128, 0, stream>>>(XL, Xgt, d_in[2], d_in[3], d_in[4],
                                           d_in[5], d_in[6], ws);
  final_kernel<<<1, 1024, 0, stream>>>(ws, (const float*)d_in[7], out);
}

// Round 15
// 25.858 us; speedup vs baseline: 26.1076x; 26.1076x over previous
//
#include <hip/hip_runtime.h>

#define LPTS 4096
#define NTOKS 512
#define TILE 32
#define CAP (LPTS + TILE)      // coord arrays sized CAP: compacted + pad tile
#define GRID_B 2080            // pair blocks (grid-stride over tiles)
#define PREP_B 16

#define LOG2E   1.44269504f
#define EPS_S   (1e-6f * LOG2E)
#define CLAMP_S (25.f * LOG2E)
#define CUT15_S (15.f * LOG2E)
#define CUT30_S (30.f * LOG2E)
#define PAD_BIG 1e15f

// ws layout:
//   wsi[5]            Lv (plain store by prep block 15)
//   ws[8 .. 8+80)     prep partials: [block b][k]  k=0..3 mse_d, k=4 mask count
//   OFF_GT:  float4 cgt4[CAP] (gt xyz scaled by log2e, meta=tok|isna<<16)
//   OFF_PX/PY/PZ: float4 per-point pred coords scaled by log2e (lanes d=0..3)
//   OFF_PART: float partials[GRID_B][5]
#define OFF_GT 512
#define OFF_PX (OFF_GT + CAP * 16)
#define OFF_PY (OFF_PX + CAP * 16)
#define OFF_PZ (OFF_PY + CAP * 16)
#define OFF_PART (OFF_PZ + CAP * 16)

static __device__ __forceinline__ float nan0(float x) {
  if (!(x == x)) return 0.f;
  return fminf(fmaxf(x, -3.402823466e38f), 3.402823466e38f);
}

// sum of 4 sigmoids = N(e)/D(e), e = exp(delta) = 2^(delta_scaled)
static __device__ __forceinline__ float sterm(float dx, float dy, float dz, float tmp) {
  float d2 = fmaf(dx, dx, fmaf(dy, dy, dz * dz));
  float pd = __builtin_amdgcn_sqrtf(d2);
  float delta = fminf(fabsf(pd + tmp), CLAMP_S);   // scaled domain
  float e = __builtin_amdgcn_exp2f(delta);         // = exp(delta_unscaled)
  float e2 = e * e;
  float e3 = e2 * e;
  float e4 = e2 * e2;
  float Nn = fmaf(0.0366994762f, e3, fmaf(0.7506558488f, e2, fmaf(3.3841830690f, e, 4.f)));
  float Dd = fmaf(0.00055308437f, e4,
             fmaf(0.0366994762f, e3, fmaf(0.3753279244f, e2, fmaf(1.1280610231f, e, 1.f))));
  return Nn * __builtin_amdgcn_rcpf(Dd);           // pad rows/cols: Dd=inf -> s=0 (finite)
}

// ---- Kernel A: detect + deterministic compact + MSE partials, no atomics ----
__global__ __launch_bounds__(256) void prep_kernel(
    const float* __restrict__ XL, const float* __restrict__ Xgt,
    const void* __restrict__ crd, const void* __restrict__ dna,
    const void* __restrict__ rna, const void* __restrict__ lig,
    const void* __restrict__ tok, float* __restrict__ ws) {
  int b = blockIdx.x, t = threadIdx.x;
  int l = b * 256 + t;
  int* wsi = (int*)ws;
  const int* toki = (const int*)tok;
  const int* crdi = (const int*)crd;
  const unsigned char* crdB = (const unsigned char*)crd;
  // full-range dtype detection, replicated per block for a consistent global decision
  __shared__ int sflags[5];
  if (t < 5) sflags[t] = 0;
  __syncthreads();
  {
    int f0 = 0;
    for (int i = t; i < LPTS / 2; i += 256) f0 |= (toki[2 * i + 1] != 0);
    if (f0) atomicOr(&sflags[0], 1);
    int f1 = 0;
    for (int i = t; i < LPTS / 4; i += 256) f1 |= ((unsigned)crdi[i] > 1u);
    if (f1) atomicOr(&sflags[1], 1);
    if (t < NTOKS / 4) {
      if ((unsigned)((const int*)dna)[t] > 1u) atomicOr(&sflags[2], 1);
      if ((unsigned)((const int*)rna)[t] > 1u) atomicOr(&sflags[3], 1);
      if ((unsigned)((const int*)lig)[t] > 1u) atomicOr(&sflags[4], 1);
    }
  }
  __syncthreads();
  bool tok64 = sflags[0] == 0;
  bool crdb = sflags[1] != 0, dnab = sflags[2] != 0,
       rnab = sflags[3] != 0, ligb = sflags[4] != 0;

  // deterministic prefix: count masked points in blocks < b (L2-hot, tiny)
  int pre = 0;
  for (int i = t; i < b * 256; i += 256)
    pre += crdb ? (crdB[i] != 0) : (crdi[i] != 0);

  // own point
  int tk = tok64 ? toki[2 * l] : toki[l];
  int tki = min(max(tk, 0), NTOKS - 1);
  int m  = crdb ? (crdB[l] != 0) : (crdi[l] != 0);
  int dn = (dnab ? (int)((const unsigned char*)dna)[tki] : ((const int*)dna)[tki]) != 0;
  int rn = (rnab ? (int)((const unsigned char*)rna)[tki] : ((const int*)rna)[tki]) != 0;
  int lg = (ligb ? (int)((const unsigned char*)lig)[tki] : ((const int*)lig)[tki]) != 0;
  float w = (1.f + 5.f * dn + 5.f * rn + 10.f * lg) * (float)m;
  float gx = nan0(Xgt[3 * l + 0]);
  float gy = nan0(Xgt[3 * l + 1]);
  float gz = nan0(Xgt[3 * l + 2]);
  int meta = (tk & 0xFFFF) | ((dn | rn) << 16);
  float xs[4], ys[4], zs[4];
  float v[5];
#pragma unroll
  for (int d = 0; d < 4; ++d) {
    xs[d] = XL[(d * LPTS + l) * 3 + 0];
    ys[d] = XL[(d * LPTS + l) * 3 + 1];
    zs[d] = XL[(d * LPTS + l) * 3 + 2];
    float dx = xs[d] - gx, dy = ys[d] - gy, dz = zs[d] - gz;
    v[d] = w * (dx * dx + dy * dy + dz * dz);   // MSE in UNSCALED domain
  }
  v[4] = (float)m;

  // block-internal ordered position + block base from prefix
  int lane = t & 63, wid = t >> 6;
  unsigned long long bal = __ballot(m != 0);
  int p = pre;
#pragma unroll
  for (int off = 32; off; off >>= 1) p += __shfl_down(p, off, 64);
  __shared__ int sw[4], wcnt[4];
  if (lane == 0) { sw[wid] = p; wcnt[wid] = __popcll(bal); }
  __syncthreads();
  int block_base = sw[0] + sw[1] + sw[2] + sw[3];
  int wbase = block_base;
  for (int q = 0; q < wid; ++q) wbase += wcnt[q];
  int pos = wbase + __popcll(bal & ((1ull << lane) - 1ull));
  float4* cgt4 = (float4*)((char*)ws + OFF_GT);
  float4* cpx  = (float4*)((char*)ws + OFF_PX);
  float4* cpy  = (float4*)((char*)ws + OFF_PY);
  float4* cpz  = (float4*)((char*)ws + OFF_PZ);
  if (m) {  // store coords PRE-SCALED by log2e for the pair kernel
    cgt4[pos] = make_float4(gx * LOG2E, gy * LOG2E, gz * LOG2E, __int_as_float(meta));
    cpx[pos] = make_float4(xs[0] * LOG2E, xs[1] * LOG2E, xs[2] * LOG2E, xs[3] * LOG2E);
    cpy[pos] = make_float4(ys[0] * LOG2E, ys[1] * LOG2E, ys[2] * LOG2E, ys[3] * LOG2E);
    cpz[pos] = make_float4(zs[0] * LOG2E, zs[1] * LOG2E, zs[2] * LOG2E, zs[3] * LOG2E);
  }
  if (b == PREP_B - 1) {
    int Lv = block_base + wcnt[0] + wcnt[1] + wcnt[2] + wcnt[3];
    if (t == 0) wsi[5] = Lv;
    if (t < TILE) {  // pad: huge gt -> gd>cutoff -> pm=0; zero pred; sentinel meta
      cgt4[Lv + t] = make_float4(PAD_BIG, PAD_BIG, PAD_BIG, __int_as_float(0x7FFFFFFF));
      float4 z = make_float4(0.f, 0.f, 0.f, 0.f);
      cpx[Lv + t] = z; cpy[Lv + t] = z; cpz[Lv + t] = z;
    }
  }
  // MSE / mask partials -> per-block plain store
#pragma unroll
  for (int k = 0; k < 5; ++k) {
    float x = v[k];
#pragma unroll
    for (int off = 32; off; off >>= 1) x += __shfl_down(x, off, 64);
    v[k] = x;
  }
  __shared__ float bred[4][5];
  if (lane == 0)
    for (int k = 0; k < 5; ++k) bred[wid][k] = v[k];
  __syncthreads();
  if (t == 0)
    for (int k = 0; k < 5; ++k)
      ws[8 + b * 5 + k] = bred[0][k] + bred[1][k] + bred[2][k] + bred[3][k];
}

// ---------- Kernel B: pair tiles, 128 thr / 8 cols per thread ----------
__global__ __launch_bounds__(128) void pair_kernel(float* __restrict__ ws) {
  const int* wsi = (const int*)ws;
  const int Lv = wsi[5];
  const int NT = (Lv + TILE - 1) >> 5;
  const int NA = NT * (NT + 1) / 2;
  const float4* cgt4 = (const float4*)((const char*)ws + OFF_GT);
  const float4* cpx  = (const float4*)((const char*)ws + OFF_PX);
  const float4* cpy  = (const float4*)((const char*)ws + OFF_PY);
  const float4* cpz  = (const float4*)((const char*)ws + OFF_PZ);
  __shared__ float4 sg[TILE], sx[TILE], sy[TILE], sz[TILE];
  __shared__ float bred[2][5];
  int t = threadIdx.x;
  int r = t & 31, g = t >> 5;      // g in 0..3, 8 cols each
  float a0 = 0.f, a1 = 0.f, a2 = 0.f, a3 = 0.f, a4 = 0.f;
  for (int b = blockIdx.x; b < NA; b += GRID_B) {
    int tj = (int)((__builtin_amdgcn_sqrtf(8.f * (float)b + 1.f) - 1.f) * 0.5f);
    while ((tj + 1) * (tj + 2) / 2 <= b) ++tj;
    while (tj * (tj + 1) / 2 > b) --tj;
    int ti = b - tj * (tj + 1) / 2;
    int i0 = ti * TILE, j0 = tj * TILE;
    __syncthreads();
    if (t < 32) sg[t] = cgt4[j0 + t];
    else if (t < 64) sx[t - 32] = cpx[j0 + t - 32];
    else if (t < 96) sy[t - 64] = cpy[j0 + t - 64];
    else sz[t - 96] = cpz[j0 + t - 96];
    __syncthreads();
    int i = i0 + r;
    float4 rg = cgt4[i], rx = cpx[i], ry = cpy[i], rz = cpz[i];
    int rmeta = __float_as_int(rg.w);
    float cutoff = (rmeta & 0x10000) ? CUT30_S : CUT15_S;
    bool diag = (ti == tj);
#pragma unroll
    for (int k = 0; k < 8; ++k) {
      int jj = g * 8 + k;
      float4 cg = sg[jj];
      float dgx = rg.x - cg.x, dgy = rg.y - cg.y, dgz = rg.z - cg.z;
      float gd = __builtin_amdgcn_sqrtf(fmaf(dgx, dgx, fmaf(dgy, dgy, dgz * dgz)));
      bool pm = (gd > 0.f) & (gd < cutoff) & (rmeta != __float_as_int(cg.w));
      if (diag) pm = pm & (jj > r);   // uniform branch; only 64/2080 blocks pay
      float pmf = pm ? 1.f : 0.f;
      float tmp = EPS_S - gd;
      float4 cx = sx[jj], cy = sy[jj], cz = sz[jj];
      float s0 = sterm(rx.x - cx.x, ry.x - cy.x, rz.x - cz.x, tmp);
      float s1 = sterm(rx.y - cx.y, ry.y - cy.y, rz.y - cz.y, tmp);
      float s2 = sterm(rx.z - cx.z, ry.z - cy.z, rz.z - cz.z, tmp);
      float s3 = sterm(rx.w - cx.w, ry.w - cy.w, rz.w - cz.w, tmp);
      a0 = fmaf(s0, pmf, a0);
      a1 = fmaf(s1, pmf, a1);
      a2 = fmaf(s2, pmf, a2);
      a3 = fmaf(s3, pmf, a3);
      a4 += pmf;
    }
  }
  // block reduce (2 waves) -> one plain store
  float v[5] = {a0, a1, a2, a3, a4};
#pragma unroll
  for (int k = 0; k < 5; ++k) {
    float x = v[k];
#pragma unroll
    for (int off = 32; off; off >>= 1) x += __shfl_down(x, off, 64);
    v[k] = x;
  }
  int wid = t >> 6, lane = t & 63;
  if (lane == 0)
    for (int k = 0; k < 5; ++k) bred[wid][k] = v[k];
  __syncthreads();
  if (t == 0) {
    float* part = (float*)((char*)ws + OFF_PART);
#pragma unroll
    for (int k = 0; k < 5; ++k)
      part[blockIdx.x * 5 + k] = bred[0][k] + bred[1][k];
  }
}

// ---------------- Kernel C: final reduce + scalar assembly ----------------
__global__ __launch_bounds__(1024) void final_kernel(
    const float* __restrict__ ws, const float* __restrict__ t_in,
    float* __restrict__ out) {
  int t = threadIdx.x;
  const float* part = (const float*)((const char*)ws + OFF_PART);
  float u[5] = {0.f, 0.f, 0.f, 0.f, 0.f};
  for (int i = t; i < GRID_B; i += 1024) {
#pragma unroll
    for (int k = 0; k < 5; ++k) u[k] += part[i * 5 + k];
  }
#pragma unroll
  for (int k = 0; k < 5; ++k) {
    float x = u[k];
#pragma unroll
    for (int off = 32; off; off >>= 1) x += __shfl_down(x, off, 64);
    u[k] = x;
  }
  __shared__ float bred[16][5];
  int wid = t >> 6, lane = t & 63;
  if (lane == 0)
    for (int k = 0; k < 5; ++k) bred[wid][k] = u[k];
  __syncthreads();
  if (t == 0) {
    float ssum[5];
#pragma unroll
    for (int k = 0; k < 5; ++k) {
      float x = 0.f;
      for (int q = 0; q < 16; ++q) x += bred[q][k];
      ssum[k] = x;
    }
    float mse[4] = {0.f, 0.f, 0.f, 0.f};
    float mask_sum = 0.f;
    for (int b = 0; b < PREP_B; ++b) {
#pragma unroll
      for (int d = 0; d < 4; ++d) mse[d] += ws[8 + b * 5 + d];
      mask_sum += ws[8 + b * 5 + 4];
    }
    float pm_sum = ssum[4];
    float tot = 0.f;
#pragma unroll
    for (int d = 0; d < 4; ++d) {
      float lmse = (mse[d] * (1.f / 3.f)) / (mask_sum + 1e-4f);
      float td = t_in[d];
      float lam = (td * td + 256.f) / (256.f * td * td);
      float ldiff = fminf(lam * lmse, 2.f);
      float lddt = 0.25f * ssum[d] / (pm_sum + 1e-6f);
      tot += 0.25f * (ldiff + (1.f - lddt));
    }
    out[0] = 4.f * tot;
  }
}

extern "C" void kernel_launch(void* const* d_in, const int* in_sizes, int n_in,
                              void* d_out, int out_size, void* d_ws, size_t ws_size,
                              hipStream_t stream) {
  (void)in_sizes; (void)n_in; (void)out_size; (void)ws_size;
  const float* XL  = (const float*)d_in[0];
  const float* Xgt = (const float*)d_in[1];
  float* ws = (float*)d_ws;
  float* out = (float*)d_out;
  prep_kernel<<<PREP_B, 256, 0, stream>>>(XL, Xgt, d_in[2], d_in[3], d_in[4],
                                          d_in[5], d_in[6], ws);
  pair_kernel<<<GRID_B, 128, 0, stream>>>(ws);
  final_kernel<<<1, 1024, 0, stream>>>(ws, (const float*)d_in[7], out);
}